// Round 2
// 1567.269 us; speedup vs baseline: 1.0098x; 1.0098x over previous
//
#include <hip/hip_runtime.h>
#include <hip/hip_bf16.h>
#include <math.h>

#define TT 2048
#define CC 1024
#define HH 16
#define DD 64
#define LL 4
#define VOCAB_N 32000

using bf16 = __hip_bfloat16;
typedef __bf16 bf16x8 __attribute__((ext_vector_type(8)));
typedef float f32x4 __attribute__((ext_vector_type(4)));

typedef unsigned int uint_gl __attribute__((address_space(1)));
typedef unsigned int uint_ld __attribute__((address_space(3)));

__device__ __forceinline__ void gload_lds16(const bf16* g, bf16* l) {
    __builtin_amdgcn_global_load_lds((const uint_gl*)g, (uint_ld*)l, 16, 0, 0);
}

#define VMCNT(n) asm volatile("s_waitcnt vmcnt(" #n ")" ::: "memory")
#define MEMFENCE asm volatile("" ::: "memory")
#define BAR() do { MEMFENCE; __builtin_amdgcn_s_barrier(); MEMFENCE; } while (0)

// ---------------- embed: x = wte[ids] + wpe ----------------
__global__ __launch_bounds__(256) void embed_kernel(const int* __restrict__ ids,
                                                    const float* __restrict__ wte,
                                                    const float* __restrict__ wpe,
                                                    float* __restrict__ x) {
    int t = blockIdx.x;
    int id = ids[t];
    int tid = threadIdx.x;
    float4 a = ((const float4*)(wte + (size_t)id * CC))[tid];
    float4 p = ((const float4*)(wpe + (size_t)t * CC))[tid];
    a.x += p.x; a.y += p.y; a.z += p.z; a.w += p.w;
    ((float4*)(x + (size_t)t * CC))[tid] = a;
}

// ---------------- layernorm (fp32 in, bf16 out), one block per row ----------------
__global__ __launch_bounds__(256) void ln_kernel(const float* __restrict__ x,
                                                 const float* __restrict__ w,
                                                 const float* __restrict__ b,
                                                 bf16* __restrict__ out) {
    int row = blockIdx.x;
    int tid = threadIdx.x;
    const float* xr = x + (size_t)row * CC;
    float4 v = ((const float4*)xr)[tid];
    float s = v.x + v.y + v.z + v.w;
    float ss = v.x * v.x + v.y * v.y + v.z * v.z + v.w * v.w;
    #pragma unroll
    for (int off = 32; off > 0; off >>= 1) {
        s += __shfl_down(s, off, 64);
        ss += __shfl_down(ss, off, 64);
    }
    __shared__ float sbuf[8];
    int wv = tid >> 6;
    if ((tid & 63) == 0) { sbuf[wv] = s; sbuf[4 + wv] = ss; }
    __syncthreads();
    s = sbuf[0] + sbuf[1] + sbuf[2] + sbuf[3];
    ss = sbuf[4] + sbuf[5] + sbuf[6] + sbuf[7];
    float mu = s * (1.0f / CC);
    float var = ss * (1.0f / CC) - mu * mu;
    float rs = rsqrtf(var + 1e-5f);
    float4 wv4 = ((const float4*)w)[tid];
    float4 bv4 = ((const float4*)b)[tid];
    size_t base = (size_t)row * CC + tid * 4;
    out[base + 0] = __float2bfloat16((v.x - mu) * rs * wv4.x + bv4.x);
    out[base + 1] = __float2bfloat16((v.y - mu) * rs * wv4.y + bv4.y);
    out[base + 2] = __float2bfloat16((v.z - mu) * rs * wv4.z + bv4.z);
    out[base + 3] = __float2bfloat16((v.w - mu) * rs * wv4.w + bv4.w);
}

// ---------------- fp32 -> bf16 convert (8 elems/thread, 16B store) ----------------
__global__ __launch_bounds__(256) void cvt_kernel(const float* __restrict__ in,
                                                  bf16* __restrict__ out, int n) {
    int i = (blockIdx.x * 256 + threadIdx.x) * 8;
    if (i < n) {
        float4 a = *(const float4*)(in + i);
        float4 b = *(const float4*)(in + i + 4);
        bf16 tmp[8];
        tmp[0] = __float2bfloat16(a.x);
        tmp[1] = __float2bfloat16(a.y);
        tmp[2] = __float2bfloat16(a.z);
        tmp[3] = __float2bfloat16(a.w);
        tmp[4] = __float2bfloat16(b.x);
        tmp[5] = __float2bfloat16(b.y);
        tmp[6] = __float2bfloat16(b.z);
        tmp[7] = __float2bfloat16(b.w);
        *(bf16x8*)(out + i) = *(const bf16x8*)tmp;
    }
}

// ---------------- GEMM: out(M,N) = A(M,K) @ W(N,K)^T + bias ----------------
// EPI: 0 = bf16 store (+bias), 1 = bf16 store gelu(v+bias), 2 = fp32 residual add (+bias), 3 = fp32 store (no bias)
// KSPLIT: blockIdx.z splits K; EPI=2 uses atomicAdd when KSPLIT>1.
template <int EPI, int KSPLIT>
__global__ __launch_bounds__(256) void gemm_bt(const bf16* __restrict__ A,
                                               const bf16* __restrict__ W,
                                               const float* __restrict__ bias,
                                               bf16* __restrict__ outb,
                                               float* __restrict__ outf,
                                               int M, int N, int K) {
    __shared__ bf16 At[128 * 32];
    __shared__ bf16 Bt[128 * 32];
    const int tid = threadIdx.x;
    const int wv = tid >> 6;
    const int ln = tid & 15;
    const int quad = (tid & 63) >> 4;
    const int wm = (wv >> 1) * 64;
    const int wn = (wv & 1) * 64;

    // panel swizzle: consecutive 16x-by-gy panels for L2 weight reuse
    const int gx = gridDim.x, gy = gridDim.y;
    int f = blockIdx.y * gx + blockIdx.x;
    int nfull = gx >> 4;
    int fullB = nfull * 16 * gy;
    int bx, by;
    if (f < fullB) {
        int p = f / (16 * gy);
        int r = f - p * (16 * gy);
        bx = p * 16 + (r & 15);
        by = r >> 4;
    } else {
        int r = f - fullB;
        int w = gx - (nfull << 4);
        bx = (nfull << 4) + r % w;
        by = r / w;
    }
    const int m0 = by * 128;
    const int n0 = bx * 128;
    const int kb = K / KSPLIT;
    const int k_beg = (KSPLIT > 1) ? blockIdx.z * kb : 0;
    const int k_end = k_beg + kb;

    f32x4 acc[4][4];
    #pragma unroll
    for (int i = 0; i < 4; i++)
        #pragma unroll
        for (int j = 0; j < 4; j++)
            #pragma unroll
            for (int r = 0; r < 4; r++) acc[i][j][r] = 0.0f;

    const int rsw = (ln >> 1) & 3;   // XOR bank swizzle key for fragment reads

    for (int k0 = k_beg; k0 < k_end; k0 += 32) {
        #pragma unroll
        for (int r = 0; r < 2; r++) {
            int ci = r * 256 + tid;
            int row = ci >> 2;
            int lc = (ci & 3) ^ ((row >> 1) & 3);   // swizzled logical chunk
            gload_lds16(A + (size_t)(m0 + row) * K + k0 + lc * 8,
                        At + (size_t)(r * 256 + wv * 64) * 8);
            gload_lds16(W + (size_t)(n0 + row) * K + k0 + lc * 8,
                        Bt + (size_t)(r * 256 + wv * 64) * 8);
        }
        __syncthreads();
        bf16x8 af[4], bfg[4];
        #pragma unroll
        for (int i = 0; i < 4; i++)
            af[i] = *(const bf16x8*)&At[(wm + i * 16 + ln) * 32 + (quad ^ rsw) * 8];
        #pragma unroll
        for (int j = 0; j < 4; j++)
            bfg[j] = *(const bf16x8*)&Bt[(wn + j * 16 + ln) * 32 + (quad ^ rsw) * 8];
        #pragma unroll
        for (int i = 0; i < 4; i++)
            #pragma unroll
            for (int j = 0; j < 4; j++)
                acc[i][j] = __builtin_amdgcn_mfma_f32_16x16x32_bf16(af[i], bfg[j], acc[i][j], 0, 0, 0);
        __syncthreads();
    }

    const bool addBias = (EPI != 3) && (KSPLIT == 1 || blockIdx.z == 0);
    #pragma unroll
    for (int j = 0; j < 4; j++) {
        int col = n0 + wn + j * 16 + ln;
        float bv = addBias ? bias[col] : 0.0f;
        #pragma unroll
        for (int i = 0; i < 4; i++) {
            int rowb = m0 + wm + i * 16 + quad * 4;
            #pragma unroll
            for (int r = 0; r < 4; r++) {
                float v = acc[i][j][r] + bv;
                size_t idx = (size_t)(rowb + r) * N + col;
                if (EPI == 0) {
                    outb[idx] = __float2bfloat16(v);
                } else if (EPI == 1) {
                    outb[idx] = __float2bfloat16(0.5f * v * (1.0f + erff(v * 0.70710678118654752f)));
                } else if (EPI == 2) {
                    if (KSPLIT > 1) atomicAdd(&outf[idx], v);
                    else outf[idx] += v;
                } else {
                    outf[idx] = v;
                }
            }
        }
    }
}

// ---------------- 256x256 8-phase GEMM (logits): out fp32 = A(M,K) @ W(N,K)^T ----------------
// 512 threads = 8 waves (2M x 4N), BK=64, double-buffered 128 KiB LDS,
// counted vmcnt (never 0 in steady state), per-phase ds_read || gload_lds || MFMA.
__device__ __forceinline__ void stage_q(const bf16* __restrict__ X, bf16* dst,
                                        int r0, int K, int k0, int q, int tid) {
    const int g = q * 512 + tid;
    const int row = g >> 3;
    const int lc = (g & 7) ^ (row & 7);      // inverse-swizzled global source
    gload_lds16(X + (size_t)(r0 + row) * K + k0 + lc * 8,
                dst + (size_t)(q * 512 + (tid & 0x1C0)) * 8);   // linear LDS dest
}

template <int QI>
__device__ __forceinline__ void rd_a(const bf16* Ab, int wm2, int ln, int quad, bf16x8 af[4][2]) {
    #pragma unroll
    for (int i = 0; i < 4; i++) {
        const int row = wm2 * 128 + QI * 64 + i * 16 + ln;
        #pragma unroll
        for (int ks = 0; ks < 2; ks++)
            af[i][ks] = *(const bf16x8*)&Ab[row * 64 + ((ks * 4 + quad) ^ (ln & 7)) * 8];
    }
}

template <int QJ>
__device__ __forceinline__ void rd_b(const bf16* Bb, int wn2, int ln, int quad, bf16x8 bfr[2][2]) {
    #pragma unroll
    for (int j = 0; j < 2; j++) {
        const int row = wn2 * 64 + QJ * 32 + j * 16 + ln;
        #pragma unroll
        for (int ks = 0; ks < 2; ks++)
            bfr[j][ks] = *(const bf16x8*)&Bb[row * 64 + ((ks * 4 + quad) ^ (ln & 7)) * 8];
    }
}

template <int QI, int QJ>
__device__ __forceinline__ void mfma_q(bf16x8 af[4][2], bf16x8 bfr[2][2], f32x4 acc[8][4]) {
    __builtin_amdgcn_s_setprio(1);
    #pragma unroll
    for (int ks = 0; ks < 2; ks++)
        #pragma unroll
        for (int i = 0; i < 4; i++)
            #pragma unroll
            for (int j = 0; j < 2; j++)
                acc[QI * 4 + i][QJ * 2 + j] =
                    __builtin_amdgcn_mfma_f32_16x16x32_bf16(af[i][ks], bfr[j][ks],
                                                            acc[QI * 4 + i][QJ * 2 + j], 0, 0, 0);
    __builtin_amdgcn_s_setprio(0);
}

__global__ __launch_bounds__(512, 2) void gemm256(const bf16* __restrict__ A,
                                                  const bf16* __restrict__ W,
                                                  float* __restrict__ out,
                                                  int M, int N, int K) {
    __shared__ bf16 As[2][256 * 64];
    __shared__ bf16 Bs[2][256 * 64];
    const int tid = threadIdx.x;
    const int ln = tid & 15;
    const int quad = (tid & 63) >> 4;
    const int wv = tid >> 6;
    const int wm2 = wv >> 2;     // 0..1
    const int wn2 = wv & 3;      // 0..3

    // XCD-contiguous, bx-major decode: each XCD owns consecutive (bx,by) tiles
    // so the 8 M-blocks sharing a 512 KB W panel hit the same private L2.
    const int cpx = gridDim.x >> 3;
    const int wg = (blockIdx.x & 7) * cpx + (blockIdx.x >> 3);
    const int byn = M >> 8;
    const int bx = wg / byn;
    const int by = wg - bx * byn;
    const int m0 = by * 256;
    const int n0 = bx * 256;

    f32x4 acc[8][4];
    #pragma unroll
    for (int i = 0; i < 8; i++)
        #pragma unroll
        for (int j = 0; j < 4; j++)
            #pragma unroll
            for (int r = 0; r < 4; r++) acc[i][j][r] = 0.0f;

    const int nt = K >> 6;

    // prologue: tile0 -> buf0 (A+B), A(1) -> buf1.  B(1) is issued at P0 of tile0.
    #pragma unroll
    for (int q = 0; q < 4; q++) stage_q(A, As[0], m0, K, 0, q, tid);
    #pragma unroll
    for (int q = 0; q < 4; q++) stage_q(W, Bs[0], n0, K, 0, q, tid);
    #pragma unroll
    for (int q = 0; q < 4; q++) stage_q(A, As[1], m0, K, 64, q, tid);

    for (int tt = 0; tt < nt; tt++) {
        const int c = tt & 1;
        const bf16* Ab = As[c];
        const bf16* Bb = Bs[c];
        bf16* An = As[c];        // A(tt+2) reuses this buffer
        bf16* Bn = Bs[c ^ 1];    // B(tt+1) goes to the other buffer

        // tile-top wait: drain this tile's loads, keep next A-tile (4 loads) in flight
        if (tt < nt - 1) { VMCNT(4); } else { VMCNT(0); }
        __builtin_amdgcn_s_barrier();
        MEMFENCE;

        bf16x8 af[4][2], bfr[2][2];

        // P0: quadrant (0,0); issue all of B(tt+1)
        if (tt + 1 < nt) {
            #pragma unroll
            for (int q = 0; q < 4; q++) stage_q(W, Bn, n0, K, (tt + 1) * 64, q, tid);
        }
        rd_a<0>(Ab, wm2, ln, quad, af);
        rd_b<0>(Bb, wn2, ln, quad, bfr);
        BAR();
        mfma_q<0, 0>(af, bfr, acc);
        BAR();

        // P1: quadrant (0,1); issue A(tt+2) quarters 0,2 (rows read only in P0)
        if (tt + 2 < nt) {
            stage_q(A, An, m0, K, (tt + 2) * 64, 0, tid);
            stage_q(A, An, m0, K, (tt + 2) * 64, 2, tid);
        }
        rd_b<1>(Bb, wn2, ln, quad, bfr);
        BAR();
        mfma_q<0, 1>(af, bfr, acc);
        BAR();

        // P2: quadrant (1,1), reuse B(qj=1) fragments
        rd_a<1>(Ab, wm2, ln, quad, af);
        BAR();
        mfma_q<1, 1>(af, bfr, acc);
        BAR();

        // P3: quadrant (1,0); issue A(tt+2) quarters 1,3 (rows read only in P2)
        if (tt + 2 < nt) {
            stage_q(A, An, m0, K, (tt + 2) * 64, 1, tid);
            stage_q(A, An, m0, K, (tt + 2) * 64, 3, tid);
        }
        rd_b<0>(Bb, wn2, ln, quad, bfr);
        BAR();
        mfma_q<1, 0>(af, bfr, acc);
        // no trailing barrier: tile-top vmcnt+barrier covers the P3->P0 hazard
    }

    // epilogue: fp32 store
    #pragma unroll
    for (int gi = 0; gi < 8; gi++)
        #pragma unroll
        for (int gj = 0; gj < 4; gj++) {
            const int rowb = m0 + wm2 * 128 + gi * 16 + quad * 4;
            const int col = n0 + wn2 * 64 + gj * 16 + ln;
            #pragma unroll
            for (int r = 0; r < 4; r++)
                out[(size_t)(rowb + r) * N + col] = acc[gi][gj][r];
        }
}

// ---------------- V transpose: qkv V-part [t][h*64+d] -> vT [h][d][t] ----------------
__global__ __launch_bounds__(256) void vtrans_kernel(const bf16* __restrict__ qkv,
                                                     bf16* __restrict__ vT) {
    const int h = blockIdx.x;
    const int t0 = blockIdx.y * 64;
    __shared__ __bf16 tl[64][72];
    const int tid = threadIdx.x;
    const int rhalf = tid >> 3;          // 0..31
    const int c8 = (tid & 7) * 8;
    #pragma unroll
    for (int rr = 0; rr < 2; rr++) {
        int row = rhalf + 32 * rr;       // t within tile
        bf16x8 v = *(const bf16x8*)(qkv + (size_t)(t0 + row) * (3 * CC) + 2 * CC + h * DD + c8);
        #pragma unroll
        for (int i = 0; i < 8; i++) tl[c8 + i][row] = v[i];
    }
    __syncthreads();
    #pragma unroll
    for (int rr = 0; rr < 2; rr++) {
        int d = rhalf + 32 * rr;
        bf16x8 o;
        #pragma unroll
        for (int i = 0; i < 8; i++) o[i] = tl[d][c8 + i];
        *(bf16x8*)(vT + (size_t)(h * DD + d) * TT + t0 + c8) = o;
    }
}

// ---------------- flash attention v2 (causal) ----------------
// grid (H, T/128), 256 threads = 4 waves; wave handles 32 q-rows.
// Computes S^T = K·Q^T (keys in MFMA rows -> cheap softmax), PV with pre-transposed V.
__global__ __launch_bounds__(256) void attn_kernel(const bf16* __restrict__ qkv,
                                                   const bf16* __restrict__ vT,
                                                   bf16* __restrict__ y) {
    const int h = blockIdx.x;
    const int q0 = blockIdx.y * 128;
    const int tid = threadIdx.x;
    const int wq = tid >> 6;
    const int ln = tid & 15;
    const int quad = (tid & 63) >> 4;
    const int wr0 = q0 + wq * 32;

    __shared__ bf16 Kt[64 * 64];         // [key][d], XOR-swizzled 16B chunks
    __shared__ bf16 Vt[64 * 64];         // [d][t],  XOR-swizzled 16B chunks
    __shared__ bf16 Pt[4][32 * 72];      // per-wave P[qlocal][j], stride 72 (144B, 16B-aligned)

    // Q fragments as MFMA B-operand: lane n=ln -> q row; k = d
    bf16x8 qf[2][2];
    #pragma unroll
    for (int qi = 0; qi < 2; qi++)
        #pragma unroll
        for (int ks = 0; ks < 2; ks++)
            qf[qi][ks] = *(const bf16x8*)(qkv + (size_t)(wr0 + qi * 16 + ln) * (3 * CC) + h * DD + ks * 32 + quad * 8);

    f32x4 oy[2][4];                      // [q group][d group]
    float mrow[2], lrow[2];
    #pragma unroll
    for (int i = 0; i < 2; i++) {
        #pragma unroll
        for (int j = 0; j < 4; j++)
            #pragma unroll
            for (int r = 0; r < 4; r++) oy[i][j][r] = 0.0f;
        mrow[i] = -INFINITY;
        lrow[i] = 0.0f;
    }

    const int ntiles = q0 / 64 + 2;
    for (int kt = 0; kt < ntiles; kt++) {
        const int kt0 = kt * 64;
        // stage K tile and V^T tile via async 16B global->LDS, XOR chunk swizzle
        #pragma unroll
        for (int r = 0; r < 2; r++) {
            int ci = r * 256 + tid;
            int row = ci >> 3;
            int lc = (ci & 7) ^ (row & 7);
            gload_lds16(qkv + (size_t)(kt0 + row) * (3 * CC) + CC + h * DD + lc * 8,
                        Kt + (size_t)(r * 256 + wq * 64) * 8);
            gload_lds16(vT + (size_t)(h * DD + row) * TT + kt0 + lc * 8,
                        Vt + (size_t)(r * 256 + wq * 64) * 8);
        }
        __syncthreads();

        if (kt0 <= wr0) {
            // S^T: A = K rows (m=key), B = Q rows (n=q)
            bf16x8 kf[4][2];
            #pragma unroll
            for (int ki = 0; ki < 4; ki++)
                #pragma unroll
                for (int ks = 0; ks < 2; ks++) {
                    int Rk = ki * 16 + ln;
                    kf[ki][ks] = *(const bf16x8*)&Kt[Rk * 64 + (((ks * 4 + quad) ^ (Rk & 7))) * 8];
                }
            f32x4 st[4][2];
            #pragma unroll
            for (int ki = 0; ki < 4; ki++)
                #pragma unroll
                for (int qi = 0; qi < 2; qi++)
                    #pragma unroll
                    for (int r = 0; r < 4; r++) st[ki][qi][r] = 0.0f;
            #pragma unroll
            for (int ks = 0; ks < 2; ks++)
                #pragma unroll
                for (int ki = 0; ki < 4; ki++)
                    #pragma unroll
                    for (int qi = 0; qi < 2; qi++)
                        st[ki][qi] = __builtin_amdgcn_mfma_f32_16x16x32_bf16(kf[ki][ks], qf[qi][ks], st[ki][qi], 0, 0, 0);

            // online softmax: row q = wr0 + qi*16 + ln holds its 16 keys in this lane (x4 quads = 64)
            const float scale = 0.125f;
            float alpha[2];
            #pragma unroll
            for (int qi = 0; qi < 2; qi++) {
                int q = wr0 + qi * 16 + ln;
                float sv[4][4];
                float mx = -INFINITY;
                #pragma unroll
                for (int ki = 0; ki < 4; ki++)
                    #pragma unroll
                    for (int r = 0; r < 4; r++) {
                        float t = st[ki][qi][r] * scale;
                        int key = kt0 + ki * 16 + quad * 4 + r;
                        if (key > q) t = -INFINITY;
                        sv[ki][r] = t;
                        mx = fmaxf(mx, t);
                    }
                mx = fmaxf(mx, __shfl_xor(mx, 16, 64));
                mx = fmaxf(mx, __shfl_xor(mx, 32, 64));
                float mnew = fmaxf(mrow[qi], mx);
                alpha[qi] = __expf(mrow[qi] - mnew);
                mrow[qi] = mnew;
                float ps = 0.0f;
                #pragma unroll
                for (int ki = 0; ki < 4; ki++)
                    #pragma unroll
                    for (int r = 0; r < 4; r++) {
                        float p = __expf(sv[ki][r] - mnew);
                        ps += p;
                        Pt[wq][(qi * 16 + ln) * 72 + ki * 16 + quad * 4 + r] = __float2bfloat16(p);
                    }
                ps += __shfl_xor(ps, 16, 64);
                ps += __shfl_xor(ps, 32, 64);
                lrow[qi] = lrow[qi] * alpha[qi] + ps;
            }

            // rescale O (rows live at quad*4+r, alpha lives at lane ln=row)
            #pragma unroll
            for (int i = 0; i < 2; i++)
                #pragma unroll
                for (int r = 0; r < 4; r++) {
                    float a = __shfl(alpha[i], quad * 4 + r, 16);
                    #pragma unroll
                    for (int dn = 0; dn < 4; dn++) oy[i][dn][r] *= a;
                }

            // O += P @ V : A = P rows (m=q), B = V^T rows (n=d)
            bf16x8 pf[2][2], vf[4][2];
            #pragma unroll
            for (int i = 0; i < 2; i++)
                #pragma unroll
                for (int ks = 0; ks < 2; ks++)
                    pf[i][ks] = *(const bf16x8*)&Pt[wq][(i * 16 + ln) * 72 + ks * 32 + quad * 8];
            #pragma unroll
            for (int dn = 0; dn < 4; dn++)
                #pragma unroll
                for (int ks = 0; ks < 2; ks++) {
                    int Rd = dn * 16 + ln;
                    vf[dn][ks] = *(const bf16x8*)&Vt[Rd * 64 + (((ks * 4 + quad) ^ (Rd & 7))) * 8];
                }
            #pragma unroll
            for (int ks = 0; ks < 2; ks++)
                #pragma unroll
                for (int i = 0; i < 2; i++)
                    #pragma unroll
                    for (int dn = 0; dn < 4; dn++)
                        oy[i][dn] = __builtin_amdgcn_mfma_f32_16x16x32_bf16(pf[i][ks], vf[dn][ks], oy[i][dn], 0, 0, 0);
        }
        __syncthreads();
    }

    // epilogue: y = O / l
    #pragma unroll
    for (int i = 0; i < 2; i++)
        #pragma unroll
        for (int r = 0; r < 4; r++) {
            float linv = 1.0f / __shfl(lrow[i], quad * 4 + r, 16);
            int row = wr0 + i * 16 + quad * 4 + r;
            #pragma unroll
            for (int dn = 0; dn < 4; dn++)
                y[(size_t)row * CC + h * DD + dn * 16 + ln] = __float2bfloat16(oy[i][dn][r] * linv);
        }
}

// ---------------- launch ----------------
extern "C" void kernel_launch(void* const* d_in, const int* in_sizes, int n_in,
                              void* d_out, int out_size, void* d_ws, size_t ws_size,
                              hipStream_t stream) {
    const int*   ids    = (const int*)d_in[0];
    const float* wte    = (const float*)d_in[1];
    const float* wpe    = (const float*)d_in[2];
    const float* ln1_w  = (const float*)d_in[3];
    const float* ln1_b  = (const float*)d_in[4];
    const float* attn_w = (const float*)d_in[5];
    const float* attn_b = (const float*)d_in[6];
    const float* proj_w = (const float*)d_in[7];
    const float* proj_b = (const float*)d_in[8];
    const float* ln2_w  = (const float*)d_in[9];
    const float* ln2_b  = (const float*)d_in[10];
    const float* fc_w   = (const float*)d_in[11];
    const float* fc_b   = (const float*)d_in[12];
    const float* fcp_w  = (const float*)d_in[13];
    const float* fcp_b  = (const float*)d_in[14];
    const float* lnf_w  = (const float*)d_in[15];
    const float* lnf_b  = (const float*)d_in[16];

    char* ws = (char*)d_ws;
    float* x    = (float*)(ws);                     // 8 MB fp32 residual
    bf16* hbuf  = (bf16*)(ws + 8388608);            // 4 MB  (T x C)
    bf16* g4buf = (bf16*)(ws + 12582912);           // 16 MB (T x 4C); reused as vT during attention
    bf16* qkvb  = (bf16*)(ws + 29360128);           // 12 MB (T x 3C)
    bf16* ybuf  = (bf16*)(ws + 41943040);           // 4 MB  (T x C)
    bf16* wbuf  = (bf16*)(ws + 46137344);           // 62.5 MB (max VOCAB x C)
    bf16* vtb   = g4buf;                            // 4 MB vT [h][d][t]

    embed_kernel<<<TT, 256, 0, stream>>>(ids, wte, wpe, x);

    for (int l = 0; l < LL; l++) {
        ln_kernel<<<TT, 256, 0, stream>>>(x, ln1_w + l * CC, ln1_b + l * CC, hbuf);

        cvt_kernel<<<(3 * CC * CC) / 2048, 256, 0, stream>>>(attn_w + (size_t)l * 3 * CC * CC, wbuf, 3 * CC * CC);
        gemm_bt<0, 1><<<dim3(3 * CC / 128, TT / 128), 256, 0, stream>>>(hbuf, wbuf, attn_b + l * 3 * CC,
                                                                        qkvb, nullptr, TT, 3 * CC, CC);

        vtrans_kernel<<<dim3(HH, TT / 64), 256, 0, stream>>>(qkvb, vtb);
        attn_kernel<<<dim3(HH, TT / 128), 256, 0, stream>>>(qkvb, vtb, ybuf);

        cvt_kernel<<<(CC * CC) / 2048, 256, 0, stream>>>(proj_w + (size_t)l * CC * CC, wbuf, CC * CC);
        gemm_bt<2, 2><<<dim3(CC / 128, TT / 128, 2), 256, 0, stream>>>(ybuf, wbuf, proj_b + l * CC,
                                                                       nullptr, x, TT, CC, CC);

        ln_kernel<<<TT, 256, 0, stream>>>(x, ln2_w + l * CC, ln2_b + l * CC, hbuf);

        cvt_kernel<<<(4 * CC * CC) / 2048, 256, 0, stream>>>(fc_w + (size_t)l * 4 * CC * CC, wbuf, 4 * CC * CC);
        gemm_bt<1, 1><<<dim3(4 * CC / 128, TT / 128), 256, 0, stream>>>(hbuf, wbuf, fc_b + l * 4 * CC,
                                                                        g4buf, nullptr, TT, 4 * CC, CC);

        cvt_kernel<<<(4 * CC * CC) / 2048, 256, 0, stream>>>(fcp_w + (size_t)l * 4 * CC * CC, wbuf, 4 * CC * CC);
        gemm_bt<2, 2><<<dim3(CC / 128, TT / 128, 2), 256, 0, stream>>>(g4buf, wbuf, fcp_b + l * CC,
                                                                       nullptr, x, TT, CC, 4 * CC);
    }

    ln_kernel<<<TT, 256, 0, stream>>>(x, lnf_w, lnf_b, hbuf);
    cvt_kernel<<<(VOCAB_N * CC) / 2048, 256, 0, stream>>>(wte, wbuf, VOCAB_N * CC);
    // logits: 256x256 8-phase pipelined GEMM, grid = (32000/256)*(2048/256) = 1000 (div by 8 XCDs)
    gemm256<<<dim3((VOCAB_N / 256) * (TT / 256)), 512, 0, stream>>>(hbuf, wbuf, (float*)d_out,
                                                                    TT, VOCAB_N, CC);
}